// Round 8
// baseline (1104.720 us; speedup 1.0000x reference)
//
#include <hip/hip_runtime.h>
#include <math.h>

#define Bn 4
#define Nn 1024
#define En 65536
#define Fn 96
#define FEn 32
#define Hn 12
// K dim for message MLP: 2F+FE = 224

// ---- MEASUREMENT ROUND: distinct rep counts so msg/attn/proj/out EACH land
// in rocprof top-5 with their own counters. wm-zero split into standalone
// kernel (unrepped) so reps measure pure compute. t_k = dur_k / REP_k.
#define REP_MSG  14
#define REP_ATTN 10
#define REP_PROJ 20
#define REP_OUT  18

// ---- out layout (floats) ----
#define OUT_UPD  0
#define OUT_WM   393216LL             // B*N*F
#define OUT_DIST 25559040LL           // + B*E*F
#define OUT_EDGE 25821184LL           // + B*E

// ---- ws layout (float words) ----
#define WS_AGG  0
#define WS_Q    393216
#define WS_K    786432
#define WS_V    1179648
#define WS_G    1572864
#define WS_AO   1966080
#define WS_LIST 2359296   // int: compacted active-edge ids (cap 65536)
#define WS_LW   2424832   // float: per-active gaussian weight
#define WS_CNT  2490368   // int: active count

#define MSG_NWAVES 1024   // 256 blocks * 4 waves; 4 edges/wave

typedef __attribute__((ext_vector_type(8))) short bf16x8;
typedef __attribute__((ext_vector_type(4))) float f32x4;

__device__ __forceinline__ float gelu_exact(float x) {
    return 0.5f * x * (1.0f + erff(x * 0.70710678118654752f));
}

// pack two f32 -> (lo,hi) bf16 pair in one u32 (RNE)
__device__ __forceinline__ unsigned cvtpk_bf16(float lo, float hi) {
    unsigned r;
    asm("v_cvt_pk_bf16_f32 %0, %1, %2" : "=v"(r) : "v"(lo), "v"(hi));
    return r;
}

// Pass 0: zero agg (1.5 MB) + counter.
__global__ void zero_kernel(float* __restrict__ agg, int* __restrict__ gcnt) {
    int i = blockIdx.x * 256 + threadIdx.x;
    const float4 z = make_float4(0.f, 0.f, 0.f, 0.f);
    float4* p = (float4*)agg;
    p[i] = z;
    p[i + 49152] = z;
    if (i == 0) gcnt[0] = 0;
}

// Pass 1a (scan): gaussian gate; copy dist/edges; block-aggregated compaction.
__global__ __launch_bounds__(1024) void scan_kernel(
        const float* __restrict__ dist, const int* __restrict__ edges,
        const float* __restrict__ sigma, const float* __restrict__ beta,
        float* __restrict__ out_dist, float* __restrict__ out_edges,
        int* __restrict__ glist, float* __restrict__ gw,
        int* __restrict__ gcnt) {
    __shared__ int wcnt[16], wbase[16], blkbase;
    int tid = threadIdx.x;
    int lane = tid & 63, wv = tid >> 6;
    int ge = blockIdx.x * 1024 + tid;
    float d = dist[ge];
    out_dist[ge] = d;
    int e0 = edges[2 * ge], e1 = edges[2 * ge + 1];
    *(float2*)&out_edges[2 * ge] = make_float2((float)e0, (float)e1);
    float sg = sigma[0], bt = beta[0];
    float t  = d * d / (2.0f * sg * sg);
    float tp = powf(t, bt);
    bool active = (tp < 90.0f);            // else w underflows f32 (ref < 1e-39)
    float w = active ? expf(-tp) : 0.0f;

    unsigned long long mask = __ballot(active);
    int lp = __popcll(mask & ((1ull << lane) - 1ull));
    if (lane == 0) wcnt[wv] = __popcll(mask);
    __syncthreads();
    if (tid == 0) {
        int a = 0;
        #pragma unroll
        for (int i = 0; i < 16; ++i) { wbase[i] = a; a += wcnt[i]; }
        blkbase = a ? atomicAdd(gcnt, a) : 0;
    }
    __syncthreads();
    if (active) {
        int pos = blkbase + wbase[wv] + lp;
        if (pos < 65536) { glist[pos] = ge; gw[pos] = w; }
    }
}

// Pass 1b (msg), x REP_MSG: four edges per wave; agg atomics last rep only.
__global__ __launch_bounds__(256) void msg_kernel(
        const int* __restrict__ glist, const float* __restrict__ gw,
        const int* __restrict__ gcnt, const int* __restrict__ edges,
        const float* __restrict__ nodes, const float* __restrict__ ef,
        const float* __restrict__ Wm, const float* __restrict__ bm,
        const float* __restrict__ g1, const float* __restrict__ b1,
        float* __restrict__ out_wm, float* __restrict__ agg) {
    __shared__ float sin_s[4][4][232];     // [wave][edge-in-quad][224+pad]
    int tid = threadIdx.x;
    int lane = tid & 63, wv = tid >> 6;
    int count = gcnt[0];
    if (count > 65536) count = 65536;
    int c2 = 64 + (lane & 31);             // upper lanes duplicate lanes 0..31
    int wid = blockIdx.x * 4 + wv;

    for (int rep = 0; rep < REP_MSG; ++rep) {
      for (int base = wid * 4; base < count; base += MSG_NWAVES * 4) {
        int   gei[4];
        float wgt[4];
        bool  val[4];
        #pragma unroll
        for (int e = 0; e < 4; ++e) {
            int ai = base + e;
            val[e] = (ai < count);
            int as = val[e] ? ai : base;   // safe clamp; padded lanes weight 0
            gei[e] = glist[as];
            wgt[e] = val[e] ? gw[ai] : 0.0f;
        }
        #pragma unroll
        for (int e = 0; e < 4; ++e) {
            int g = gei[e];
            int b = g >> 16;
            int e0 = edges[2 * g], e1 = edges[2 * g + 1];
            const float* n0 = nodes + ((size_t)b * Nn + e0) * 96;
            const float* n1 = nodes + ((size_t)b * Nn + e1) * 96;
            const float* ep = ef + (size_t)g * 32;
            #pragma unroll
            for (int ii = 0; ii < 4; ++ii) {
                int i = ii * 64 + lane;
                if (i < 224) {
                    float v = (i < 96) ? n0[i] : (i < 192) ? n1[i - 96] : ep[i - 192];
                    sin_s[wv][e][i] = v;
                }
            }
        }
        float acc[4][2];
        #pragma unroll
        for (int e = 0; e < 4; ++e) { acc[e][0] = bm[lane]; acc[e][1] = bm[c2]; }
        #pragma unroll 8
        for (int i = 0; i < 224; ++i) {
            float w1 = Wm[i * 96 + lane];
            float w2 = Wm[i * 96 + c2];
            #pragma unroll
            for (int e = 0; e < 4; ++e) {
                float a = sin_s[wv][e][i];             // LDS broadcast
                acc[e][0] = fmaf(a, w1, acc[e][0]);
                acc[e][1] = fmaf(a, w2, acc[e][1]);
            }
        }
        #pragma unroll
        for (int e = 0; e < 4; ++e) {
            if (!val[e]) continue;
            float y1 = gelu_exact(acc[e][0]);
            float y2 = gelu_exact(acc[e][1]);
            float c2v = (lane < 32) ? y2 : 0.0f;
            float sum  = y1 + c2v;
            float sum2 = y1 * y1 + c2v * c2v;
            #pragma unroll
            for (int off = 1; off < 64; off <<= 1) {
                sum  += __shfl_xor(sum, off);
                sum2 += __shfl_xor(sum2, off);
            }
            float mean = sum * (1.0f / 96.0f);
            float var  = sum2 * (1.0f / 96.0f) - mean * mean;
            float rs   = rsqrtf(var + 1e-3f);
            int g = gei[e];
            int b = g >> 16;
            int e1 = edges[2 * g + 1];
            float* aggp = agg + ((size_t)b * Nn + e1) * 96;
            float* wmp  = out_wm + (size_t)g * 96;
            float o1 = ((y1 - mean) * rs * g1[lane] + b1[lane]) * wgt[e];
            wmp[lane] = o1;
            if (rep == REP_MSG - 1) atomicAdd(&aggp[lane], o1);
            if (lane < 32) {
                float o2 = ((y2 - mean) * rs * g1[c2] + b1[c2]) * wgt[e];
                wmp[c2] = o2;
                if (rep == REP_MSG - 1) atomicAdd(&aggp[c2], o2);
            }
        }
      }
    }
}

// Pass 1c (wmzero): standalone inactive-row zero fill of out_wm (~100 MB).
// One 256-edge chunk per block; active test bitwise-identical to scan's.
__global__ __launch_bounds__(256) void wmzero_kernel(
        const float* __restrict__ dist, const float* __restrict__ sigma,
        const float* __restrict__ beta, float* __restrict__ out_wm) {
    __shared__ int s_act[256];
    int tid = threadIdx.x;
    int c = blockIdx.x;
    {
        int ge = c * 256 + tid;
        float d = dist[ge];
        float sg = sigma[0], bt = beta[0];
        float t = d * d / (2.0f * sg * sg);
        s_act[tid] = (powf(t, bt) < 90.0f) ? 1 : 0;
    }
    __syncthreads();
    const float4 z = make_float4(0.f, 0.f, 0.f, 0.f);
    float4* wm4 = (float4*)out_wm + (size_t)c * 6144;   // 256 rows * 24 float4
    for (int p = tid; p < 6144; p += 256) {
        if (!s_act[p / 24]) wm4[p] = z;
    }
}

// Pass 2 (proj), x REP_PROJ: q/k/v/gate projections, head-major output.
__global__ void proj_kernel(const float* __restrict__ nodes, const float* __restrict__ agg,
                            const float* __restrict__ Wq, const float* __restrict__ bq,
                            const float* __restrict__ Wk, const float* __restrict__ bk,
                            const float* __restrict__ Wv, const float* __restrict__ bv,
                            const float* __restrict__ Wg, const float* __restrict__ bg,
                            float* __restrict__ qo, float* __restrict__ ko,
                            float* __restrict__ vo, float* __restrict__ go) {
    __shared__ float xs[32][200];   // padded; row byte-stride 800 = 50*16 (16B aligned)
    __shared__ float Wt[64 * 96];
    int tid = threadIdx.x;
    int m = blockIdx.y;
    const float* W    = (m == 0) ? Wq : (m == 1) ? Wk : (m == 2) ? Wv : Wg;
    const float* bias = (m == 0) ? bq : (m == 1) ? bk : (m == 2) ? bv : bg;
    float* outp       = (m == 0) ? qo : (m == 1) ? ko : (m == 2) ? vo : go;
    int row0 = blockIdx.x * 32;
    int b = row0 >> 10, n0 = row0 & 1023;
    for (int rep = 0; rep < REP_PROJ; ++rep) {
      __syncthreads();
      for (int i = tid; i < 32 * 192; i += 256) {
          int r = i / 192, k = i % 192;
          size_t row = row0 + r;
          xs[r][k] = (k < 96) ? nodes[row * 96 + k] : agg[row * 96 + (k - 96)];
      }
      int rg = tid >> 4;              // 0..15 (2 rows each)
      int cg = tid & 15;              // 0..15 (6 cols each)
      float acc[12];
      #pragma unroll
      for (int c = 0; c < 12; ++c) acc[c] = 0.0f;
      for (int kc = 0; kc < 3; ++kc) {
          __syncthreads();
          {
              float4* Wt4 = (float4*)Wt;
              const float4* Wg4 = (const float4*)(W + kc * 64 * 96);
              for (int i = tid; i < 1536; i += 256) Wt4[i] = Wg4[i];
          }
          __syncthreads();
          #pragma unroll 4
          for (int k = 0; k < 64; ++k) {
              float a0 = xs[rg * 2 + 0][kc * 64 + k];
              float a1 = xs[rg * 2 + 1][kc * 64 + k];
              #pragma unroll
              for (int c = 0; c < 6; ++c) {
                  float wv_ = Wt[k * 96 + cg * 6 + c];
                  acc[c]     = fmaf(a0, wv_, acc[c]);
                  acc[6 + c] = fmaf(a1, wv_, acc[6 + c]);
              }
          }
      }
      #pragma unroll
      for (int i = 0; i < 2; ++i) {
          #pragma unroll
          for (int c = 0; c < 6; ++c) {
              int col = cg * 6 + c;
              float v = acc[i * 6 + c] + bias[col];
              if (m == 3) v = 1.0f / (1.0f + expf(-v));
              xs[rg * 2 + i][col] = v;
          }
      }
      __syncthreads();
      float4* out4 = (float4*)outp;
      for (int j = tid; j < 768; j += 256) {
          int h = j >> 6, idx = j & 63;
          int r = idx >> 1, half = idx & 1;
          float4 v = *(const float4*)&xs[r][h * 8 + half * 4];
          out4[(((size_t)b * Hn + h) * Nn + n0) * 2 + idx] = v;
      }
    }
}

// Pass 3 (attn), x REP_ATTN: MFMA bf16 attention (round-7 structure).
__global__ __launch_bounds__(256, 4) void attn_kernel(
        const float* __restrict__ qp, const float* __restrict__ kp,
        const float* __restrict__ vp, const float* __restrict__ gp,
        float* __restrict__ ao) {
    __shared__ __align__(16) unsigned short K_s[1024][8];     // 16 KB
    __shared__ __align__(16) unsigned short Vt_s[9][1032];    // 18.1 KB
    __shared__ __align__(16) unsigned short P_s[4][16][32];   // 4 KB
    int tid = threadIdx.x;
    int bh = blockIdx.y;                    // b*H + h
    int lane = tid & 63, wv = tid >> 6;
    size_t hb = (size_t)bh * (Nn * 8);
    const float* kc = kp + hb;
    const float* vc = vp + hb;

    for (int rep = 0; rep < REP_ATTN; ++rep) {
      __syncthreads();
      {
          const float2* k2 = (const float2*)kc;
          unsigned* kw = (unsigned*)&K_s[0][0];
          for (int i = tid; i < 4096; i += 256) {
              float2 v = k2[i];
              kw[i] = cvtpk_bf16(v.x, v.y);
          }
      }
      for (int i = tid; i < 8192; i += 256) {
          float v = vc[i];
          int k = i >> 3, n = i & 7;
          Vt_s[n][k] = (unsigned short)cvtpk_bf16(v, v);
      }
      {
          unsigned* ow = (unsigned*)&Vt_s[8][0];
          for (int i = tid; i < 516; i += 256) ow[i] = 0x3F803F80u;  // bf16(1.0) x2
      }
      const float scale = 0.35355339059327376f;
      int qbase = blockIdx.x * 64 + wv * 16;
      bf16x8 aq = {0, 0, 0, 0, 0, 0, 0, 0};
      if (lane < 16) {
          const float* qr = qp + hb + (size_t)(qbase + lane) * 8;
          float4 qa = *(const float4*)qr;
          float4 qb2 = *(const float4*)(qr + 4);
          union { unsigned u[4]; bf16x8 v; } U;
          U.u[0] = cvtpk_bf16(qa.x * scale, qa.y * scale);
          U.u[1] = cvtpk_bf16(qa.z * scale, qa.w * scale);
          U.u[2] = cvtpk_bf16(qb2.x * scale, qb2.y * scale);
          U.u[3] = cvtpk_bf16(qb2.z * scale, qb2.w * scale);
          aq = U.v;
      }
      __syncthreads();

      const bf16x8 zero8 = {0, 0, 0, 0, 0, 0, 0, 0};
      const f32x4 zero4 = {0.f, 0.f, 0.f, 0.f};
      f32x4 o = zero4;
      int n16 = lane & 15, grp = lane >> 4;
      for (int c = 0; c < 32; ++c) {
          bf16x8 bk0 = zero8, bk1 = zero8;
          if (lane < 16) {
              bk0 = *(const bf16x8*)&K_s[c * 32 + lane][0];
              bk1 = *(const bf16x8*)&K_s[c * 32 + 16 + lane][0];
          }
          f32x4 s0 = __builtin_amdgcn_mfma_f32_16x16x32_bf16(aq, bk0, zero4, 0, 0, 0);
          f32x4 s1 = __builtin_amdgcn_mfma_f32_16x16x32_bf16(aq, bk1, zero4, 0, 0, 0);
          #pragma unroll
          for (int r = 0; r < 4; ++r) {
              unsigned pk = cvtpk_bf16(__expf(s0[r]), __expf(s1[r]));
              int row = grp * 4 + r;
              P_s[wv][row][n16]      = (unsigned short)pk;
              P_s[wv][row][16 + n16] = (unsigned short)(pk >> 16);
          }
          bf16x8 pa = *(const bf16x8*)&P_s[wv][n16][grp * 8];
          bf16x8 bv = zero8;
          if (n16 <= 8) bv = *(const bf16x8*)&Vt_s[n16][c * 32 + grp * 8];
          o = __builtin_amdgcn_mfma_f32_16x16x32_bf16(pa, bv, o, 0, 0, 0);
      }

      #pragma unroll
      for (int r = 0; r < 4; ++r) {
          float L = __shfl(o[r], (lane & 48) | 8);
          if (n16 < 8) {
              int q = qbase + grp * 4 + r;
              size_t off = hb + (size_t)q * 8 + n16;
              ao[off] = o[r] / L * gp[off];
          }
      }
    }
}

// Pass 4 (out), x REP_OUT: out @ Wo + bo -> GELU -> LayerNorm.
__global__ __launch_bounds__(512) void out_kernel(
        const float* __restrict__ ao, const float* __restrict__ Wo,
        const float* __restrict__ bo, const float* __restrict__ g2,
        const float* __restrict__ b2, float* __restrict__ out0) {
    __shared__ float Wsh[96 * 96];
    __shared__ float as_[32][104];   // row byte-stride 416 = 26*16 (16B aligned)
    int tid = threadIdx.x;
    int row0 = blockIdx.x * 32;
    int b = row0 >> 10, n0 = row0 & 1023;
    for (int rep = 0; rep < REP_OUT; ++rep) {
      __syncthreads();
      {
          float4* W4 = (float4*)Wsh;
          const float4* Wg4 = (const float4*)Wo;
          for (int i = tid; i < 2304; i += 512) W4[i] = Wg4[i];
      }
      const float4* ao4 = (const float4*)ao;
      for (int j = tid; j < 768; j += 512) {
          int h = j >> 6, idx = j & 63;
          int r = idx >> 1, half = idx & 1;
          float4 v = ao4[(((size_t)b * Hn + h) * Nn + n0) * 2 + idx];
          *(float4*)&as_[r][h * 8 + half * 4] = v;
      }
      __syncthreads();
      int r = tid >> 4, cg = tid & 15;   // 32 rows, 6 cols per thread
      float acc[6];
      #pragma unroll
      for (int c = 0; c < 6; ++c) acc[c] = 0.0f;
      for (int k = 0; k < 96; ++k) {
          float a = as_[r][k];
          #pragma unroll
          for (int c = 0; c < 6; ++c)
              acc[c] = fmaf(a, Wsh[k * 96 + cg * 6 + c], acc[c]);
      }
      float yv[6];
      float sum = 0.0f, sum2 = 0.0f;
      #pragma unroll
      for (int c = 0; c < 6; ++c) {
          float t = acc[c] + bo[cg * 6 + c];
          float g = gelu_exact(t);
          yv[c] = g;
          sum += g; sum2 += g * g;
      }
      #pragma unroll
      for (int off = 1; off < 16; off <<= 1) {
          sum  += __shfl_xor(sum, off);
          sum2 += __shfl_xor(sum2, off);
      }
      float mean = sum * (1.0f / 96.0f);
      float var  = sum2 * (1.0f / 96.0f) - mean * mean;
      float rs   = rsqrtf(var + 1e-3f);
      size_t row = row0 + r;
      #pragma unroll
      for (int c = 0; c < 6; ++c)
          out0[row * 96 + cg * 6 + c] = (yv[c] - mean) * rs * g2[cg * 6 + c] + b2[cg * 6 + c];
    }
}

extern "C" void kernel_launch(void* const* d_in, const int* in_sizes, int n_in,
                              void* d_out, int out_size, void* d_ws, size_t ws_size,
                              hipStream_t stream) {
    const float* nodes = (const float*)d_in[0];
    const float* ef    = (const float*)d_in[1];
    const float* dist  = (const float*)d_in[2];
    const int*   edges = (const int*)d_in[3];
    const float* Wm = (const float*)d_in[4];
    const float* bm = (const float*)d_in[5];
    const float* g1 = (const float*)d_in[6];
    const float* b1 = (const float*)d_in[7];
    const float* Wq = (const float*)d_in[8];
    const float* bq = (const float*)d_in[9];
    const float* Wk = (const float*)d_in[10];
    const float* bk = (const float*)d_in[11];
    const float* Wv = (const float*)d_in[12];
    const float* bv = (const float*)d_in[13];
    const float* Wg = (const float*)d_in[14];
    const float* bg = (const float*)d_in[15];
    const float* Wo = (const float*)d_in[16];
    const float* bo = (const float*)d_in[17];
    const float* g2 = (const float*)d_in[18];
    const float* b2 = (const float*)d_in[19];
    const float* sigma = (const float*)d_in[20];
    const float* beta  = (const float*)d_in[21];

    float* out = (float*)d_out;
    float* ws  = (float*)d_ws;

    float* agg  = ws + WS_AGG;
    float* qb   = ws + WS_Q;
    float* kb   = ws + WS_K;
    float* vb   = ws + WS_V;
    float* gwb  = ws + WS_G;
    float* aob  = ws + WS_AO;
    int*   glist = (int*)(ws + WS_LIST);
    float* glw   = ws + WS_LW;
    int*   gcnt  = (int*)(ws + WS_CNT);

    zero_kernel<<<192, 256, 0, stream>>>(agg, gcnt);

    scan_kernel<<<Bn * En / 1024, 1024, 0, stream>>>(
        dist, edges, sigma, beta, out + OUT_DIST, out + OUT_EDGE, glist, glw, gcnt);

    msg_kernel<<<256, 256, 0, stream>>>(
        glist, glw, gcnt, edges, nodes, ef, Wm, bm, g1, b1, out + OUT_WM, agg);

    wmzero_kernel<<<1024, 256, 0, stream>>>(dist, sigma, beta, out + OUT_WM);

    dim3 gp_(128, 4);
    proj_kernel<<<gp_, 256, 0, stream>>>(
        nodes, agg, Wq, bq, Wk, bk, Wv, bv, Wg, bg, qb, kb, vb, gwb);

    dim3 ga(16, Bn * Hn);
    attn_kernel<<<ga, 256, 0, stream>>>(qb, kb, vb, gwb, aob);

    out_kernel<<<Bn * Nn / 32, 512, 0, stream>>>(aob, Wo, bo, g2, b2, out + OUT_UPD);
}

// Round 9
// 130.714 us; speedup vs baseline: 8.4514x; 8.4514x over previous
//
#include <hip/hip_runtime.h>
#include <math.h>

#define Bn 4
#define Nn 1024
#define En 65536
#define Fn 96
#define FEn 32
#define Hn 12
// K dim for message MLP: 2F+FE = 224

// ---- out layout (floats) ----
#define OUT_UPD  0
#define OUT_WM   393216LL             // B*N*F
#define OUT_DIST 25559040LL           // + B*E*F
#define OUT_EDGE 25821184LL           // + B*E

// ---- ws layout (float words) ----
#define WS_AGG  0
#define WS_Q    393216
#define WS_K    786432
#define WS_V    1179648
#define WS_G    1572864
#define WS_AO   1966080
#define WS_LIST 2359296   // int: compacted active-edge ids (cap 65536)
#define WS_LW   2424832   // float: per-active gaussian weight
#define WS_CNT  2490368   // int: active count

#define MSG_BLOCKS 208    // 16 edges/block; grid-stride covers overflow
#define MSG_NWAVES (MSG_BLOCKS * 4)

typedef __attribute__((ext_vector_type(8))) short bf16x8;
typedef __attribute__((ext_vector_type(4))) float f32x4;

__device__ __forceinline__ float gelu_exact(float x) {
    return 0.5f * x * (1.0f + erff(x * 0.70710678118654752f));
}

// pack two f32 -> (lo,hi) bf16 pair in one u32 (RNE)
__device__ __forceinline__ unsigned cvtpk_bf16(float lo, float hi) {
    unsigned r;
    asm("v_cvt_pk_bf16_f32 %0, %1, %2" : "=v"(r) : "v"(lo), "v"(hi));
    return r;
}

// Zero the inactive rows of one 256-edge chunk of out_wm (96 KB).
// Active test bitwise-identical to scan's -> active/inactive rows partition.
__device__ __forceinline__ void zero_wm_chunk(int c, const float* __restrict__ dist,
                                              const float* __restrict__ sigma,
                                              const float* __restrict__ beta,
                                              float* __restrict__ out_wm,
                                              int tid, int nthr, int* s_act) {
    if (tid < 256) {
        int ge = c * 256 + tid;
        float d = dist[ge];
        float sg = sigma[0], bt = beta[0];
        float t = d * d / (2.0f * sg * sg);
        s_act[tid] = (powf(t, bt) < 90.0f) ? 1 : 0;
    }
    __syncthreads();
    const float4 z = make_float4(0.f, 0.f, 0.f, 0.f);
    float4* wm4 = (float4*)out_wm + (size_t)c * 6144;   // 256 rows * 24 float4
    for (int p = tid; p < 6144; p += nthr) {
        if (!s_act[p / 24]) wm4[p] = z;
    }
}

// Pass 0: zero agg (1.5 MB) + counter.
__global__ void zero_kernel(float* __restrict__ agg, int* __restrict__ gcnt) {
    int i = blockIdx.x * 256 + threadIdx.x;
    const float4 z = make_float4(0.f, 0.f, 0.f, 0.f);
    float4* p = (float4*)agg;
    p[i] = z;
    p[i + 49152] = z;
    if (i == 0) gcnt[0] = 0;
}

// Pass 1a (scan): gaussian gate; copy dist/edges; block-aggregated compaction
// (one global atomic per 1024-thread block).
__global__ __launch_bounds__(1024) void scan_kernel(
        const float* __restrict__ dist, const int* __restrict__ edges,
        const float* __restrict__ sigma, const float* __restrict__ beta,
        float* __restrict__ out_dist, float* __restrict__ out_edges,
        int* __restrict__ glist, float* __restrict__ gw,
        int* __restrict__ gcnt) {
    __shared__ int wcnt[16], wbase[16], blkbase;
    int tid = threadIdx.x;
    int lane = tid & 63, wv = tid >> 6;
    int ge = blockIdx.x * 1024 + tid;
    float d = dist[ge];
    out_dist[ge] = d;
    int e0 = edges[2 * ge], e1 = edges[2 * ge + 1];
    *(float2*)&out_edges[2 * ge] = make_float2((float)e0, (float)e1);
    float sg = sigma[0], bt = beta[0];
    float t  = d * d / (2.0f * sg * sg);
    float tp = powf(t, bt);
    bool active = (tp < 90.0f);            // else w underflows f32 (ref < 1e-39)
    float w = active ? expf(-tp) : 0.0f;

    unsigned long long mask = __ballot(active);
    int lp = __popcll(mask & ((1ull << lane) - 1ull));
    if (lane == 0) wcnt[wv] = __popcll(mask);
    __syncthreads();
    if (tid == 0) {
        int a = 0;
        #pragma unroll
        for (int i = 0; i < 16; ++i) { wbase[i] = a; a += wcnt[i]; }
        blkbase = a ? atomicAdd(gcnt, a) : 0;
    }
    __syncthreads();
    if (active) {
        int pos = blkbase + wbase[wv] + lp;
        if (pos < 65536) { glist[pos] = ge; gw[pos] = w; }
    }
}

// Pass 1b (msg): Wm staged in LDS (86 KB, fits in 160 KB/CU) -> removes the
// per-chunk global-load latency chain that round-8 diagnosed (~20us). Four
// edges per wave; 16 edges per block; grid-stride for overflow.
__global__ __launch_bounds__(256) void msg_kernel(
        const int* __restrict__ glist, const float* __restrict__ gw,
        const int* __restrict__ gcnt, const int* __restrict__ edges,
        const float* __restrict__ nodes, const float* __restrict__ ef,
        const float* __restrict__ Wm, const float* __restrict__ bm,
        const float* __restrict__ g1, const float* __restrict__ b1,
        float* __restrict__ out_wm, float* __restrict__ agg) {
    __shared__ float Wm_s[224 * 96];       // 86016 B
    __shared__ float sin_s[4][4][232];     // 14848 B
    int tid = threadIdx.x;
    int count = gcnt[0];
    if (count > 65536) count = 65536;
    if ((int)blockIdx.x * 16 >= count) return;
    {
        float4* Ws4 = (float4*)Wm_s;
        const float4* Wg4 = (const float4*)Wm;
        for (int i = tid; i < 5376; i += 256) Ws4[i] = Wg4[i];
    }
    __syncthreads();
    int lane = tid & 63, wv = tid >> 6;
    int c2 = 64 + (lane & 31);             // upper lanes duplicate lanes 0..31
    int wid = blockIdx.x * 4 + wv;

    for (int base = wid * 4; base < count; base += MSG_NWAVES * 4) {
        int   gei[4];
        float wgt[4];
        bool  val[4];
        #pragma unroll
        for (int e = 0; e < 4; ++e) {
            int ai = base + e;
            val[e] = (ai < count);
            int as = val[e] ? ai : base;   // safe clamp; padded lanes weight 0
            gei[e] = glist[as];
            wgt[e] = val[e] ? gw[ai] : 0.0f;
        }
        #pragma unroll
        for (int e = 0; e < 4; ++e) {
            int g = gei[e];
            int b = g >> 16;
            int e0 = edges[2 * g], e1 = edges[2 * g + 1];
            const float* n0 = nodes + ((size_t)b * Nn + e0) * 96;
            const float* n1 = nodes + ((size_t)b * Nn + e1) * 96;
            const float* ep = ef + (size_t)g * 32;
            #pragma unroll
            for (int ii = 0; ii < 4; ++ii) {
                int i = ii * 64 + lane;
                if (i < 224) {
                    float v = (i < 96) ? n0[i] : (i < 192) ? n1[i - 96] : ep[i - 192];
                    sin_s[wv][e][i] = v;
                }
            }
        }
        float acc[4][2];
        #pragma unroll
        for (int e = 0; e < 4; ++e) { acc[e][0] = bm[lane]; acc[e][1] = bm[c2]; }
        #pragma unroll 8
        for (int i = 0; i < 224; ++i) {
            float w1 = Wm_s[i * 96 + lane];
            float w2 = Wm_s[i * 96 + c2];
            #pragma unroll
            for (int e = 0; e < 4; ++e) {
                float a = sin_s[wv][e][i];             // LDS broadcast
                acc[e][0] = fmaf(a, w1, acc[e][0]);
                acc[e][1] = fmaf(a, w2, acc[e][1]);
            }
        }
        #pragma unroll
        for (int e = 0; e < 4; ++e) {
            if (!val[e]) continue;
            float y1 = gelu_exact(acc[e][0]);
            float y2 = gelu_exact(acc[e][1]);
            float c2v = (lane < 32) ? y2 : 0.0f;
            float sum  = y1 + c2v;
            float sum2 = y1 * y1 + c2v * c2v;
            #pragma unroll
            for (int off = 1; off < 64; off <<= 1) {
                sum  += __shfl_xor(sum, off);
                sum2 += __shfl_xor(sum2, off);
            }
            float mean = sum * (1.0f / 96.0f);
            float var  = sum2 * (1.0f / 96.0f) - mean * mean;
            float rs   = rsqrtf(var + 1e-3f);
            int g = gei[e];
            int b = g >> 16;
            int e1 = edges[2 * g + 1];
            float* aggp = agg + ((size_t)b * Nn + e1) * 96;
            float* wmp  = out_wm + (size_t)g * 96;
            float o1 = ((y1 - mean) * rs * g1[lane] + b1[lane]) * wgt[e];
            wmp[lane] = o1;
            atomicAdd(&aggp[lane], o1);
            if (lane < 32) {
                float o2 = ((y2 - mean) * rs * g1[c2] + b1[c2]) * wgt[e];
                wmp[c2] = o2;
                atomicAdd(&aggp[c2], o2);
            }
        }
    }
}

// Pass 2 (proj): wave = 64 rows (row=lane) x 24 cols. W read via wave-uniform
// scalar loads (s_load, zero LDS/VMEM cost per FMA); X staged TRANSPOSED
// xs[k][row] (stride 65 -> conflict-free) -> ONE ds_read per 24 FMAs (was 8
// per 12, the round-8 diagnosed LDS-issue bottleneck). Head-major float4
// stores direct from registers. Also zeroes wm chunks 768..1023.
__global__ __launch_bounds__(256) void proj_kernel(
        const float* __restrict__ nodes, const float* __restrict__ agg,
        const float* __restrict__ Wq, const float* __restrict__ bq,
        const float* __restrict__ Wk, const float* __restrict__ bk,
        const float* __restrict__ Wv, const float* __restrict__ bv,
        const float* __restrict__ Wg, const float* __restrict__ bg,
        float* __restrict__ qo, float* __restrict__ ko,
        float* __restrict__ vo, float* __restrict__ go,
        const float* __restrict__ dist, const float* __restrict__ sigma,
        const float* __restrict__ beta, float* __restrict__ out_wm) {
    __shared__ float xs[192][65];   // transposed X tile, 49920 B
    __shared__ int s_act[256];
    int tid = threadIdx.x;
    int m = blockIdx.y;
    zero_wm_chunk(768 + m * 64 + blockIdx.x, dist, sigma, beta, out_wm, tid, 256, s_act);

    const float* W    = (m == 0) ? Wq : (m == 1) ? Wk : (m == 2) ? Wv : Wg;
    const float* bias = (m == 0) ? bq : (m == 1) ? bk : (m == 2) ? bv : bg;
    float* outp       = (m == 0) ? qo : (m == 1) ? ko : (m == 2) ? vo : go;
    int row0 = blockIdx.x * 64;
    int b = row0 >> 10, n0 = row0 & 1023;

    for (int i = tid; i < 64 * 192; i += 256) {
        int r = i / 192, k = i % 192;
        size_t row = (size_t)row0 + r;
        xs[k][r] = (k < 96) ? nodes[row * 96 + k] : agg[row * 96 + (k - 96)];
    }
    __syncthreads();

    int lane = tid & 63;
    int wcol = __builtin_amdgcn_readfirstlane((tid >> 6) * 24);
    const float* Wp = W + wcol;       // wave-uniform -> scalar loads
    const float* bp = bias + wcol;
    float acc[24];
    #pragma unroll
    for (int c = 0; c < 24; ++c) acc[c] = bp[c];
    for (int k = 0; k < 192; ++k) {
        float a = xs[k][lane];
        #pragma unroll
        for (int c = 0; c < 24; ++c)
            acc[c] = fmaf(a, Wp[k * 96 + c], acc[c]);
    }
    if (m == 3) {
        #pragma unroll
        for (int c = 0; c < 24; ++c) acc[c] = 1.0f / (1.0f + expf(-acc[c]));
    }
    float4* out4 = (float4*)outp;
    int h0 = wcol >> 3;               // 24 cols = 3 heads
    #pragma unroll
    for (int hh = 0; hh < 3; ++hh) {
        size_t base = (((size_t)b * Hn + (h0 + hh)) * Nn + (n0 + lane)) * 2;
        out4[base]     = make_float4(acc[hh*8+0], acc[hh*8+1], acc[hh*8+2], acc[hh*8+3]);
        out4[base + 1] = make_float4(acc[hh*8+4], acc[hh*8+5], acc[hh*8+6], acc[hh*8+7]);
    }
}

// Pass 3: MFMA bf16 attention (round-7 structure) + wm-zero chunks 0..767.
__global__ __launch_bounds__(256, 4) void attn_kernel(
        const float* __restrict__ qp, const float* __restrict__ kp,
        const float* __restrict__ vp, const float* __restrict__ gp,
        float* __restrict__ ao,
        const float* __restrict__ dist, const float* __restrict__ sigma,
        const float* __restrict__ beta, float* __restrict__ out_wm) {
    __shared__ __align__(16) unsigned short K_s[1024][8];     // 16 KB
    __shared__ __align__(16) unsigned short Vt_s[9][1032];    // 18.1 KB
    __shared__ __align__(16) unsigned short P_s[4][16][32];   // 4 KB
    __shared__ int s_act[256];
    int tid = threadIdx.x;
    zero_wm_chunk(blockIdx.y * 16 + blockIdx.x, dist, sigma, beta, out_wm, tid, 256, s_act);

    int bh = blockIdx.y;                    // b*H + h
    int lane = tid & 63, wv = tid >> 6;
    size_t hb = (size_t)bh * (Nn * 8);
    const float* kc = kp + hb;
    const float* vc = vp + hb;

    {
        const float2* k2 = (const float2*)kc;
        unsigned* kw = (unsigned*)&K_s[0][0];
        for (int i = tid; i < 4096; i += 256) {
            float2 v = k2[i];
            kw[i] = cvtpk_bf16(v.x, v.y);
        }
    }
    for (int i = tid; i < 8192; i += 256) {
        float v = vc[i];
        int k = i >> 3, n = i & 7;
        Vt_s[n][k] = (unsigned short)cvtpk_bf16(v, v);
    }
    {
        unsigned* ow = (unsigned*)&Vt_s[8][0];
        for (int i = tid; i < 516; i += 256) ow[i] = 0x3F803F80u;  // bf16(1.0) x2
    }
    const float scale = 0.35355339059327376f;
    int qbase = blockIdx.x * 64 + wv * 16;
    bf16x8 aq = {0, 0, 0, 0, 0, 0, 0, 0};
    if (lane < 16) {
        const float* qr = qp + hb + (size_t)(qbase + lane) * 8;
        float4 qa = *(const float4*)qr;
        float4 qb2 = *(const float4*)(qr + 4);
        union { unsigned u[4]; bf16x8 v; } U;
        U.u[0] = cvtpk_bf16(qa.x * scale, qa.y * scale);
        U.u[1] = cvtpk_bf16(qa.z * scale, qa.w * scale);
        U.u[2] = cvtpk_bf16(qb2.x * scale, qb2.y * scale);
        U.u[3] = cvtpk_bf16(qb2.z * scale, qb2.w * scale);
        aq = U.v;
    }
    __syncthreads();

    const bf16x8 zero8 = {0, 0, 0, 0, 0, 0, 0, 0};
    const f32x4 zero4 = {0.f, 0.f, 0.f, 0.f};
    f32x4 o = zero4;
    int n16 = lane & 15, grp = lane >> 4;
    for (int c = 0; c < 32; ++c) {
        bf16x8 bk0 = zero8, bk1 = zero8;
        if (lane < 16) {
            bk0 = *(const bf16x8*)&K_s[c * 32 + lane][0];
            bk1 = *(const bf16x8*)&K_s[c * 32 + 16 + lane][0];
        }
        f32x4 s0 = __builtin_amdgcn_mfma_f32_16x16x32_bf16(aq, bk0, zero4, 0, 0, 0);
        f32x4 s1 = __builtin_amdgcn_mfma_f32_16x16x32_bf16(aq, bk1, zero4, 0, 0, 0);
        #pragma unroll
        for (int r = 0; r < 4; ++r) {
            unsigned pk = cvtpk_bf16(__expf(s0[r]), __expf(s1[r]));
            int row = grp * 4 + r;
            P_s[wv][row][n16]      = (unsigned short)pk;
            P_s[wv][row][16 + n16] = (unsigned short)(pk >> 16);
        }
        bf16x8 pa = *(const bf16x8*)&P_s[wv][n16][grp * 8];
        bf16x8 bv = zero8;
        if (n16 <= 8) bv = *(const bf16x8*)&Vt_s[n16][c * 32 + grp * 8];
        o = __builtin_amdgcn_mfma_f32_16x16x32_bf16(pa, bv, o, 0, 0, 0);
    }

    #pragma unroll
    for (int r = 0; r < 4; ++r) {
        float L = __shfl(o[r], (lane & 48) | 8);
        if (n16 < 8) {
            int q = qbase + grp * 4 + r;
            size_t off = hb + (size_t)q * 8 + n16;
            ao[off] = o[r] / L * gp[off];
        }
    }
}

// Pass 4 (out): same scalar-W structure as proj. 8 waves x 12 cols, 64 rows
// (row=lane), k=96; transposed as_[k][row]; LN via cross-wave LDS reduce.
__global__ __launch_bounds__(512) void out_kernel(
        const float* __restrict__ ao, const float* __restrict__ Wo,
        const float* __restrict__ bo, const float* __restrict__ g2,
        const float* __restrict__ b2, float* __restrict__ out0) {
    __shared__ float as_[96][65];      // 24960 B
    __shared__ float2 red_s[8][64];    // 4096 B
    int tid = threadIdx.x;
    int row0 = blockIdx.x * 64;
    int b = row0 >> 10, n0 = row0 & 1023;
    const float4* ao4 = (const float4*)ao;
    for (int j = tid; j < 1536; j += 512) {
        int h = j >> 7, rem = j & 127, n = rem >> 1, half = rem & 1;
        float4 v = ao4[(((size_t)b * Hn + h) * Nn + (n0 + n)) * 2 + half];
        int kb = h * 8 + half * 4;
        as_[kb + 0][n] = v.x; as_[kb + 1][n] = v.y;
        as_[kb + 2][n] = v.z; as_[kb + 3][n] = v.w;
    }
    __syncthreads();
    int lane = tid & 63, w = tid >> 6;
    int wcol = __builtin_amdgcn_readfirstlane(w * 12);
    const float* Wp = Wo + wcol;       // wave-uniform -> scalar loads
    float acc[12];
    #pragma unroll
    for (int c = 0; c < 12; ++c) acc[c] = 0.0f;
    for (int k = 0; k < 96; ++k) {
        float a = as_[k][lane];
        #pragma unroll
        for (int c = 0; c < 12; ++c)
            acc[c] = fmaf(a, Wp[k * 96 + c], acc[c]);
    }
    float y[12];
    float sum = 0.0f, sum2 = 0.0f;
    #pragma unroll
    for (int c = 0; c < 12; ++c) {
        float t = acc[c] + bo[wcol + c];
        float g = gelu_exact(t);
        y[c] = g; sum += g; sum2 += g * g;
    }
    red_s[w][lane] = make_float2(sum, sum2);
    __syncthreads();
    float S = 0.0f, S2 = 0.0f;
    #pragma unroll
    for (int i = 0; i < 8; ++i) { float2 p = red_s[i][lane]; S += p.x; S2 += p.y; }
    float mean = S * (1.0f / 96.0f);
    float var  = S2 * (1.0f / 96.0f) - mean * mean;
    float rs   = rsqrtf(var + 1e-3f);
    size_t row = (size_t)row0 + lane;
    #pragma unroll
    for (int c = 0; c < 12; ++c)
        y[c] = (y[c] - mean) * rs * g2[wcol + c] + b2[wcol + c];
    float4* o4 = (float4*)&out0[row * 96 + wcol];
    o4[0] = make_float4(y[0], y[1], y[2],  y[3]);
    o4[1] = make_float4(y[4], y[5], y[6],  y[7]);
    o4[2] = make_float4(y[8], y[9], y[10], y[11]);
}

extern "C" void kernel_launch(void* const* d_in, const int* in_sizes, int n_in,
                              void* d_out, int out_size, void* d_ws, size_t ws_size,
                              hipStream_t stream) {
    const float* nodes = (const float*)d_in[0];
    const float* ef    = (const float*)d_in[1];
    const float* dist  = (const float*)d_in[2];
    const int*   edges = (const int*)d_in[3];
    const float* Wm = (const float*)d_in[4];
    const float* bm = (const float*)d_in[5];
    const float* g1 = (const float*)d_in[6];
    const float* b1 = (const float*)d_in[7];
    const float* Wq = (const float*)d_in[8];
    const float* bq = (const float*)d_in[9];
    const float* Wk = (const float*)d_in[10];
    const float* bk = (const float*)d_in[11];
    const float* Wv = (const float*)d_in[12];
    const float* bv = (const float*)d_in[13];
    const float* Wg = (const float*)d_in[14];
    const float* bg = (const float*)d_in[15];
    const float* Wo = (const float*)d_in[16];
    const float* bo = (const float*)d_in[17];
    const float* g2 = (const float*)d_in[18];
    const float* b2 = (const float*)d_in[19];
    const float* sigma = (const float*)d_in[20];
    const float* beta  = (const float*)d_in[21];

    float* out = (float*)d_out;
    float* ws  = (float*)d_ws;

    float* agg  = ws + WS_AGG;
    float* qb   = ws + WS_Q;
    float* kb   = ws + WS_K;
    float* vb   = ws + WS_V;
    float* gwb  = ws + WS_G;
    float* aob  = ws + WS_AO;
    int*   glist = (int*)(ws + WS_LIST);
    float* glw   = ws + WS_LW;
    int*   gcnt  = (int*)(ws + WS_CNT);

    zero_kernel<<<192, 256, 0, stream>>>(agg, gcnt);

    scan_kernel<<<Bn * En / 1024, 1024, 0, stream>>>(
        dist, edges, sigma, beta, out + OUT_DIST, out + OUT_EDGE, glist, glw, gcnt);

    msg_kernel<<<MSG_BLOCKS, 256, 0, stream>>>(
        glist, glw, gcnt, edges, nodes, ef, Wm, bm, g1, b1, out + OUT_WM, agg);

    dim3 gp_(64, 4);
    proj_kernel<<<gp_, 256, 0, stream>>>(
        nodes, agg, Wq, bq, Wk, bk, Wv, bv, Wg, bg, qb, kb, vb, gwb,
        dist, sigma, beta, out + OUT_WM);

    dim3 ga(16, Bn * Hn);
    attn_kernel<<<ga, 256, 0, stream>>>(qb, kb, vb, gwb, aob,
                                        dist, sigma, beta, out + OUT_WM);

    out_kernel<<<Bn * Nn / 64, 512, 0, stream>>>(aob, Wo, bo, g2, b2, out + OUT_UPD);
}

// Round 10
// 110.232 us; speedup vs baseline: 10.0217x; 1.1858x over previous
//
#include <hip/hip_runtime.h>
#include <math.h>

#define Bn 4
#define Nn 1024
#define En 65536
#define Fn 96
#define FEn 32
#define Hn 12
// K dim for message MLP: 2F+FE = 224

// ---- out layout (floats) ----
#define OUT_UPD  0
#define OUT_WM   393216LL             // B*N*F
#define OUT_DIST 25559040LL           // + B*E*F
#define OUT_EDGE 25821184LL           // + B*E

// ---- ws layout (float words) ----
#define WS_AGG  0
#define WS_Q    393216
#define WS_K    786432
#define WS_V    1179648
#define WS_G    1572864
#define WS_AO   1966080
#define WS_LIST 2359296   // int: compacted active-edge ids (cap 65536)
#define WS_LW   2424832   // float: per-active gaussian weight
#define WS_CNT  2490368   // int: active count

#define MSG_BLOCKS 832    // 4 waves * 4 edges = 16 edges/block -> 1 quad/wave

typedef __attribute__((ext_vector_type(8))) short bf16x8;
typedef __attribute__((ext_vector_type(4))) float f32x4;

__device__ __forceinline__ float gelu_exact(float x) {
    return 0.5f * x * (1.0f + erff(x * 0.70710678118654752f));
}

// pack two f32 -> (lo,hi) bf16 pair in one u32 (RNE)
__device__ __forceinline__ unsigned cvtpk_bf16(float lo, float hi) {
    unsigned r;
    asm("v_cvt_pk_bf16_f32 %0, %1, %2" : "=v"(r) : "v"(lo), "v"(hi));
    return r;
}

// Zero the inactive rows of one 256-edge chunk of out_wm (96 KB).
// Active test bitwise-identical to scan's -> active/inactive rows partition.
__device__ __forceinline__ void zero_wm_chunk(int c, const float* __restrict__ dist,
                                              const float* __restrict__ sigma,
                                              const float* __restrict__ beta,
                                              float* __restrict__ out_wm,
                                              int tid, int nthr, int* s_act) {
    if (tid < 256) {
        int ge = c * 256 + tid;
        float d = dist[ge];
        float sg = sigma[0], bt = beta[0];
        float t = d * d / (2.0f * sg * sg);
        s_act[tid] = (powf(t, bt) < 90.0f) ? 1 : 0;
    }
    __syncthreads();
    const float4 z = make_float4(0.f, 0.f, 0.f, 0.f);
    float4* wm4 = (float4*)out_wm + (size_t)c * 6144;   // 256 rows * 24 float4
    for (int p = tid; p < 6144; p += nthr) {
        if (!s_act[p / 24]) wm4[p] = z;
    }
}

// Pass 0: zero agg (1.5 MB) + counter.
__global__ void zero_kernel(float* __restrict__ agg, int* __restrict__ gcnt) {
    int i = blockIdx.x * 256 + threadIdx.x;
    const float4 z = make_float4(0.f, 0.f, 0.f, 0.f);
    float4* p = (float4*)agg;
    p[i] = z;
    p[i + 49152] = z;
    if (i == 0) gcnt[0] = 0;
}

// Pass 1a (scan): gaussian gate; copy dist/edges; block-aggregated compaction
// (one global atomic per 1024-thread block; round-5 measured 25us -> ~3us).
__global__ __launch_bounds__(1024) void scan_kernel(
        const float* __restrict__ dist, const int* __restrict__ edges,
        const float* __restrict__ sigma, const float* __restrict__ beta,
        float* __restrict__ out_dist, float* __restrict__ out_edges,
        int* __restrict__ glist, float* __restrict__ gw,
        int* __restrict__ gcnt) {
    __shared__ int wcnt[16], wbase[16], blkbase;
    int tid = threadIdx.x;
    int lane = tid & 63, wv = tid >> 6;
    int ge = blockIdx.x * 1024 + tid;
    float d = dist[ge];
    out_dist[ge] = d;
    int e0 = edges[2 * ge], e1 = edges[2 * ge + 1];
    *(float2*)&out_edges[2 * ge] = make_float2((float)e0, (float)e1);
    float sg = sigma[0], bt = beta[0];
    float t  = d * d / (2.0f * sg * sg);
    float tp = powf(t, bt);
    bool active = (tp < 90.0f);            // else w underflows f32 (ref < 1e-39)
    float w = active ? expf(-tp) : 0.0f;

    unsigned long long mask = __ballot(active);
    int lp = __popcll(mask & ((1ull << lane) - 1ull));
    if (lane == 0) wcnt[wv] = __popcll(mask);
    __syncthreads();
    if (tid == 0) {
        int a = 0;
        #pragma unroll
        for (int i = 0; i < 16; ++i) { wbase[i] = a; a += wcnt[i]; }
        blkbase = a ? atomicAdd(gcnt, a) : 0;
    }
    __syncthreads();
    if (active) {
        int pos = blkbase + wbase[wv] + lp;
        if (pos < 65536) { glist[pos] = ge; gw[pos] = w; }
    }
}

// Pass 1b (msg): round-7 structure (Wm from global/L2), but 832 blocks so
// each wave does exactly ONE 4-edge quad -> more parallel Wm streams.
__global__ __launch_bounds__(256) void msg_kernel(
        const int* __restrict__ glist, const float* __restrict__ gw,
        const int* __restrict__ gcnt, const int* __restrict__ edges,
        const float* __restrict__ nodes, const float* __restrict__ ef,
        const float* __restrict__ Wm, const float* __restrict__ bm,
        const float* __restrict__ g1, const float* __restrict__ b1,
        float* __restrict__ out_wm, float* __restrict__ agg) {
    __shared__ float sin_s[4][4][232];     // [wave][edge-in-quad][224+pad]
    int tid = threadIdx.x;
    int lane = tid & 63, wv = tid >> 6;
    int count = gcnt[0];
    if (count > 65536) count = 65536;
    if ((int)blockIdx.x * 16 >= count) return;
    int c2 = 64 + (lane & 31);             // upper lanes duplicate lanes 0..31
    int wid = blockIdx.x * 4 + wv;

    for (int base = wid * 4; base < count; base += MSG_BLOCKS * 16) {
        int   gei[4];
        float wgt[4];
        bool  val[4];
        #pragma unroll
        for (int e = 0; e < 4; ++e) {
            int ai = base + e;
            val[e] = (ai < count);
            int as = val[e] ? ai : base;   // safe clamp; padded lanes weight 0
            gei[e] = glist[as];
            wgt[e] = val[e] ? gw[ai] : 0.0f;
        }
        #pragma unroll
        for (int e = 0; e < 4; ++e) {
            int g = gei[e];
            int b = g >> 16;
            int e0 = edges[2 * g], e1 = edges[2 * g + 1];
            const float* n0 = nodes + ((size_t)b * Nn + e0) * 96;
            const float* n1 = nodes + ((size_t)b * Nn + e1) * 96;
            const float* ep = ef + (size_t)g * 32;
            #pragma unroll
            for (int ii = 0; ii < 4; ++ii) {
                int i = ii * 64 + lane;
                if (i < 224) {
                    float v = (i < 96) ? n0[i] : (i < 192) ? n1[i - 96] : ep[i - 192];
                    sin_s[wv][e][i] = v;
                }
            }
        }
        float acc[4][2];
        #pragma unroll
        for (int e = 0; e < 4; ++e) { acc[e][0] = bm[lane]; acc[e][1] = bm[c2]; }
        #pragma unroll 8
        for (int i = 0; i < 224; ++i) {
            float w1 = Wm[i * 96 + lane];
            float w2 = Wm[i * 96 + c2];
            #pragma unroll
            for (int e = 0; e < 4; ++e) {
                float a = sin_s[wv][e][i];             // LDS broadcast
                acc[e][0] = fmaf(a, w1, acc[e][0]);
                acc[e][1] = fmaf(a, w2, acc[e][1]);
            }
        }
        #pragma unroll
        for (int e = 0; e < 4; ++e) {
            if (!val[e]) continue;
            float y1 = gelu_exact(acc[e][0]);
            float y2 = gelu_exact(acc[e][1]);
            float c2v = (lane < 32) ? y2 : 0.0f;
            float sum  = y1 + c2v;
            float sum2 = y1 * y1 + c2v * c2v;
            #pragma unroll
            for (int off = 1; off < 64; off <<= 1) {
                sum  += __shfl_xor(sum, off);
                sum2 += __shfl_xor(sum2, off);
            }
            float mean = sum * (1.0f / 96.0f);
            float var  = sum2 * (1.0f / 96.0f) - mean * mean;
            float rs   = rsqrtf(var + 1e-3f);
            int g = gei[e];
            int b = g >> 16;
            int e1 = edges[2 * g + 1];
            float* aggp = agg + ((size_t)b * Nn + e1) * 96;
            float* wmp  = out_wm + (size_t)g * 96;
            float o1 = ((y1 - mean) * rs * g1[lane] + b1[lane]) * wgt[e];
            wmp[lane] = o1;
            atomicAdd(&aggp[lane], o1);
            if (lane < 32) {
                float o2 = ((y2 - mean) * rs * g1[c2] + b1[c2]) * wgt[e];
                wmp[c2] = o2;
                atomicAdd(&aggp[c2], o2);
            }
        }
    }
}

// Pass 2 (proj): W staged in LDS, read at WAVE-UNIFORM addresses (hardware
// broadcast, single-address LDS reads -> ~7 LDS per 24 FMAs); X transposed
// xs[k][row] (stride 64, lane-consecutive -> conflict-free). Wave w handles
// cols w*24..w*24+23 for all 64 rows (row = lane). 1 block/CU (120 KB LDS),
// 256 blocks = one full round. Also zeroes wm chunks 768..1023.
__global__ __launch_bounds__(256, 1) void proj_kernel(
        const float* __restrict__ nodes, const float* __restrict__ agg,
        const float* __restrict__ Wq, const float* __restrict__ bq,
        const float* __restrict__ Wk, const float* __restrict__ bk,
        const float* __restrict__ Wv, const float* __restrict__ bv,
        const float* __restrict__ Wg, const float* __restrict__ bg,
        float* __restrict__ qo, float* __restrict__ ko,
        float* __restrict__ vo, float* __restrict__ go,
        const float* __restrict__ dist, const float* __restrict__ sigma,
        const float* __restrict__ beta, float* __restrict__ out_wm) {
    __shared__ float xs[192][64];   // transposed X tile, 49152 B
    __shared__ float Ws[192 * 96];  // 73728 B
    __shared__ int s_act[256];
    int tid = threadIdx.x;
    int m = blockIdx.y;
    zero_wm_chunk(768 + m * 64 + blockIdx.x, dist, sigma, beta, out_wm, tid, 256, s_act);

    const float* W    = (m == 0) ? Wq : (m == 1) ? Wk : (m == 2) ? Wv : Wg;
    const float* bias = (m == 0) ? bq : (m == 1) ? bk : (m == 2) ? bv : bg;
    float* outp       = (m == 0) ? qo : (m == 1) ? ko : (m == 2) ? vo : go;
    int row0 = blockIdx.x * 64;
    int b = row0 >> 10, n0 = row0 & 1023;

    // stage W (coalesced float4)
    {
        float4* Ws4 = (float4*)Ws;
        const float4* Wg4 = (const float4*)W;
        for (int i = tid; i < 4608; i += 256) Ws4[i] = Wg4[i];
    }
    // stage X transposed: i -> (r = i%64, k4 = i/64) so LDS stores are
    // lane-consecutive in r (bank = r mod 32, 2/bank = free)
    for (int i = tid; i < 3072; i += 256) {
        int r = i & 63, k4 = i >> 6;
        size_t row = (size_t)row0 + r;
        float4 v = (k4 < 24) ? *(const float4*)&nodes[row * 96 + k4 * 4]
                             : *(const float4*)&agg[row * 96 + (k4 - 24) * 4];
        int k = k4 * 4;
        xs[k][r] = v.x; xs[k + 1][r] = v.y; xs[k + 2][r] = v.z; xs[k + 3][r] = v.w;
    }
    __syncthreads();

    int lane = tid & 63;
    int wcol = __builtin_amdgcn_readfirstlane((tid >> 6) * 24);
    float acc[24];
    #pragma unroll
    for (int c = 0; c < 24; ++c) acc[c] = bias[wcol + c];
    for (int k = 0; k < 192; ++k) {
        float a = xs[k][lane];                 // conflict-free
        const float* wr = &Ws[k * 96 + wcol];  // wave-uniform -> LDS broadcast
        #pragma unroll
        for (int c = 0; c < 24; ++c)
            acc[c] = fmaf(a, wr[c], acc[c]);
    }
    if (m == 3) {
        #pragma unroll
        for (int c = 0; c < 24; ++c) acc[c] = 1.0f / (1.0f + expf(-acc[c]));
    }
    float4* out4 = (float4*)outp;
    int h0 = wcol >> 3;               // 24 cols = 3 heads
    #pragma unroll
    for (int hh = 0; hh < 3; ++hh) {
        size_t base = (((size_t)b * Hn + (h0 + hh)) * Nn + (n0 + lane)) * 2;
        out4[base]     = make_float4(acc[hh*8+0], acc[hh*8+1], acc[hh*8+2], acc[hh*8+3]);
        out4[base + 1] = make_float4(acc[hh*8+4], acc[hh*8+5], acc[hh*8+6], acc[hh*8+7]);
    }
}

// Pass 3: MFMA bf16 attention (round-7 structure) with cheaper V-transpose
// staging: paired float4 loads + u32 stores (8 f4-loads + 16 u32-stores per
// thread vs 32 scalar loads + 32 u16 stores). wm-zero chunks 0..767.
__global__ __launch_bounds__(256, 4) void attn_kernel(
        const float* __restrict__ qp, const float* __restrict__ kp,
        const float* __restrict__ vp, const float* __restrict__ gp,
        float* __restrict__ ao,
        const float* __restrict__ dist, const float* __restrict__ sigma,
        const float* __restrict__ beta, float* __restrict__ out_wm) {
    __shared__ __align__(16) unsigned short K_s[1024][8];     // 16 KB
    __shared__ __align__(16) unsigned short Vt_s[9][1032];    // 18.1 KB
    __shared__ __align__(16) unsigned short P_s[4][16][32];   // 4 KB
    __shared__ int s_act[256];
    int tid = threadIdx.x;
    zero_wm_chunk(blockIdx.y * 16 + blockIdx.x, dist, sigma, beta, out_wm, tid, 256, s_act);

    int bh = blockIdx.y;                    // b*H + h
    int lane = tid & 63, wv = tid >> 6;
    size_t hb = (size_t)bh * (Nn * 8);
    const float* kc = kp + hb;
    const float* vc = vp + hb;

    // ---- stage K as bf16 [k][d] ----
    {
        const float2* k2 = (const float2*)kc;
        unsigned* kw = (unsigned*)&K_s[0][0];
        for (int i = tid; i < 4096; i += 256) {
            float2 v = k2[i];
            kw[i] = cvtpk_bf16(v.x, v.y);
        }
    }
    // ---- stage V transposed via k-pairs: Vt32[d][kp] = pack(V[2kp][d], V[2kp+1][d]) ----
    {
        const float4* v4 = (const float4*)vc;
        for (int i = tid; i < 1024; i += 256) {
            int kp2 = i >> 1, dq = i & 1;
            float4 a = v4[kp2 * 4 + dq];       // V[2kp][dq*4..+3]
            float4 b = v4[kp2 * 4 + 2 + dq];   // V[2kp+1][dq*4..+3]
            int d0 = dq * 4;
            ((unsigned*)&Vt_s[d0 + 0][0])[kp2] = cvtpk_bf16(a.x, b.x);
            ((unsigned*)&Vt_s[d0 + 1][0])[kp2] = cvtpk_bf16(a.y, b.y);
            ((unsigned*)&Vt_s[d0 + 2][0])[kp2] = cvtpk_bf16(a.z, b.z);
            ((unsigned*)&Vt_s[d0 + 3][0])[kp2] = cvtpk_bf16(a.w, b.w);
        }
        unsigned* ow = (unsigned*)&Vt_s[8][0];
        for (int i = tid; i < 516; i += 256) ow[i] = 0x3F803F80u;  // bf16(1.0) x2
    }
    const float scale = 0.35355339059327376f;
    int qbase = blockIdx.x * 64 + wv * 16;
    bf16x8 aq = {0, 0, 0, 0, 0, 0, 0, 0};
    if (lane < 16) {
        const float* qr = qp + hb + (size_t)(qbase + lane) * 8;
        float4 qa = *(const float4*)qr;
        float4 qb2 = *(const float4*)(qr + 4);
        union { unsigned u[4]; bf16x8 v; } U;
        U.u[0] = cvtpk_bf16(qa.x * scale, qa.y * scale);
        U.u[1] = cvtpk_bf16(qa.z * scale, qa.w * scale);
        U.u[2] = cvtpk_bf16(qb2.x * scale, qb2.y * scale);
        U.u[3] = cvtpk_bf16(qb2.z * scale, qb2.w * scale);
        aq = U.v;
    }
    __syncthreads();

    const bf16x8 zero8 = {0, 0, 0, 0, 0, 0, 0, 0};
    const f32x4 zero4 = {0.f, 0.f, 0.f, 0.f};
    f32x4 o = zero4;
    int n16 = lane & 15, grp = lane >> 4;
    for (int c = 0; c < 32; ++c) {
        bf16x8 bk0 = zero8, bk1 = zero8;
        if (lane < 16) {
            bk0 = *(const bf16x8*)&K_s[c * 32 + lane][0];
            bk1 = *(const bf16x8*)&K_s[c * 32 + 16 + lane][0];
        }
        f32x4 s0 = __builtin_amdgcn_mfma_f32_16x16x32_bf16(aq, bk0, zero4, 0, 0, 0);
        f32x4 s1 = __builtin_amdgcn_mfma_f32_16x16x32_bf16(aq, bk1, zero4, 0, 0, 0);
        #pragma unroll
        for (int r = 0; r < 4; ++r) {
            unsigned pk = cvtpk_bf16(__expf(s0[r]), __expf(s1[r]));
            int row = grp * 4 + r;
            P_s[wv][row][n16]      = (unsigned short)pk;
            P_s[wv][row][16 + n16] = (unsigned short)(pk >> 16);
        }
        bf16x8 pa = *(const bf16x8*)&P_s[wv][n16][grp * 8];
        bf16x8 bv = zero8;
        if (n16 <= 8) bv = *(const bf16x8*)&Vt_s[n16][c * 32 + grp * 8];
        o = __builtin_amdgcn_mfma_f32_16x16x32_bf16(pa, bv, o, 0, 0, 0);
    }

    #pragma unroll
    for (int r = 0; r < 4; ++r) {
        float L = __shfl(o[r], (lane & 48) | 8);
        if (n16 < 8) {
            int q = qbase + grp * 4 + r;
            size_t off = hb + (size_t)q * 8 + n16;
            ao[off] = o[r] / L * gp[off];
        }
    }
}

// Pass 4 (out): same broadcast-W structure as proj. Wave w = cols w*24..+23,
// row = lane (64 rows/block); as_T[k][row] conflict-free; Wo in LDS (36 KB);
// LN via cross-wave LDS reduce. 64 blocks, 2 blocks/CU.
__global__ __launch_bounds__(256) void out_kernel(
        const float* __restrict__ ao, const float* __restrict__ Wo,
        const float* __restrict__ bo, const float* __restrict__ g2,
        const float* __restrict__ b2, float* __restrict__ out0) {
    __shared__ float as_[96][64];      // 24576 B
    __shared__ float Ws[96 * 96];      // 36864 B
    __shared__ float2 red_s[4][64];    // 2048 B
    int tid = threadIdx.x;
    int row0 = blockIdx.x * 64;
    int b = row0 >> 10, n0 = row0 & 1023;
    {
        float4* W4 = (float4*)Ws;
        const float4* Wg4 = (const float4*)Wo;
        for (int i = tid; i < 2304; i += 256) W4[i] = Wg4[i];
    }
    // gather head-major ao -> transposed as_[k][n] (stores lane-consecutive in n)
    const float2* ao2 = (const float2*)ao;
    for (int i = tid; i < 3072; i += 256) {       // 64 n * 48 (h, dpair)
        int n = i & 63, hd = i >> 6;              // hd = h*4 + dpair
        int h = hd >> 2, dp = hd & 3;
        float2 v = ao2[(((size_t)b * Hn + h) * Nn + (n0 + n)) * 4 + dp];
        as_[h * 8 + dp * 2][n]     = v.x;
        as_[h * 8 + dp * 2 + 1][n] = v.y;
    }
    __syncthreads();
    int lane = tid & 63, w = tid >> 6;
    int wcol = __builtin_amdgcn_readfirstlane(w * 24);
    float acc[24];
    #pragma unroll
    for (int c = 0; c < 24; ++c) acc[c] = bo[wcol + c];
    for (int k = 0; k < 96; ++k) {
        float a = as_[k][lane];                // conflict-free
        const float* wr = &Ws[k * 96 + wcol];  // wave-uniform -> broadcast
        #pragma unroll
        for (int c = 0; c < 24; ++c)
            acc[c] = fmaf(a, wr[c], acc[c]);
    }
    float y[24];
    float sum = 0.0f, sum2 = 0.0f;
    #pragma unroll
    for (int c = 0; c < 24; ++c) {
        float g = gelu_exact(acc[c]);
        y[c] = g; sum += g; sum2 += g * g;
    }
    red_s[w][lane] = make_float2(sum, sum2);
    __syncthreads();
    float S = 0.0f, S2 = 0.0f;
    #pragma unroll
    for (int i = 0; i < 4; ++i) { float2 p = red_s[i][lane]; S += p.x; S2 += p.y; }
    float mean = S * (1.0f / 96.0f);
    float var  = S2 * (1.0f / 96.0f) - mean * mean;
    float rs   = rsqrtf(var + 1e-3f);
    size_t row = (size_t)row0 + lane;
    #pragma unroll
    for (int c = 0; c < 24; ++c)
        y[c] = (y[c] - mean) * rs * g2[wcol + c] + b2[wcol + c];
    float4* o4 = (float4*)&out0[row * 96 + wcol];
    #pragma unroll
    for (int q = 0; q < 6; ++q)
        o4[q] = make_float4(y[q*4], y[q*4+1], y[q*4+2], y[q*4+3]);
}

extern "C" void kernel_launch(void* const* d_in, const int* in_sizes, int n_in,
                              void* d_out, int out_size, void* d_ws, size_t ws_size,
                              hipStream_t stream) {
    const float* nodes = (const float*)d_in[0];
    const float* ef    = (const float*)d_in[1];
    const float* dist  = (const float*)d_in[2];
    const int*   edges = (const int*)d_in[3];
    const float* Wm = (const float*)d_in[4];
    const float* bm = (const float*)d_in[5];
    const float* g1 = (const float*)d_in[6];
    const float* b1 = (const float*)d_in[7];
    const float* Wq = (const float*)d_in[8];
    const float* bq = (const float*)d_in[9];
    const float* Wk = (const float*)d_in[10];
    const float* bk = (const float*)d_in[11];
    const float* Wv = (const float*)d_in[12];
    const float* bv = (const float*)d_in[13];
    const float* Wg = (const float*)d_in[14];
    const float* bg = (const float*)d_in[15];
    const float* Wo = (const float*)d_in[16];
    const float* bo = (const float*)d_in[17];
    const float* g2 = (const float*)d_in[18];
    const float* b2 = (const float*)d_in[19];
    const float* sigma = (const float*)d_in[20];
    const float* beta  = (const float*)d_in[21];

    float* out = (float*)d_out;
    float* ws  = (float*)d_ws;

    float* agg  = ws + WS_AGG;
    float* qb   = ws + WS_Q;
    float* kb   = ws + WS_K;
    float* vb   = ws + WS_V;
    float* gwb  = ws + WS_G;
    float* aob  = ws + WS_AO;
    int*   glist = (int*)(ws + WS_LIST);
    float* glw   = ws + WS_LW;
    int*   gcnt  = (int*)(ws + WS_CNT);

    zero_kernel<<<192, 256, 0, stream>>>(agg, gcnt);

    scan_kernel<<<Bn * En / 1024, 1024, 0, stream>>>(
        dist, edges, sigma, beta, out + OUT_DIST, out + OUT_EDGE, glist, glw, gcnt);

    msg_kernel<<<MSG_BLOCKS, 256, 0, stream>>>(
        glist, glw, gcnt, edges, nodes, ef, Wm, bm, g1, b1, out + OUT_WM, agg);

    dim3 gp_(64, 4);
    proj_kernel<<<gp_, 256, 0, stream>>>(
        nodes, agg, Wq, bq, Wk, bk, Wv, bv, Wg, bg, qb, kb, vb, gwb,
        dist, sigma, beta, out + OUT_WM);

    dim3 ga(16, Bn * Hn);
    attn_kernel<<<ga, 256, 0, stream>>>(qb, kb, vb, gwb, aob,
                                        dist, sigma, beta, out + OUT_WM);

    out_kernel<<<Bn * Nn / 64, 256, 0, stream>>>(aob, Wo, bo, g2, b2, out + OUT_UPD);
}

// Round 11
// 103.096 us; speedup vs baseline: 10.7155x; 1.0692x over previous
//
#include <hip/hip_runtime.h>
#include <math.h>

#define Bn 4
#define Nn 1024
#define En 65536
#define Fn 96
#define FEn 32
#define Hn 12
// K dim for message MLP: 2F+FE = 224

// ---- out layout (floats) ----
#define OUT_UPD  0
#define OUT_WM   393216LL             // B*N*F
#define OUT_DIST 25559040LL           // + B*E*F
#define OUT_EDGE 25821184LL           // + B*E

// ---- ws layout (float words) ----
#define WS_AGG  0
#define WS_Q    393216
#define WS_K    786432
#define WS_V    1179648
#define WS_G    1572864
#define WS_AO   1966080

typedef __attribute__((ext_vector_type(8))) short bf16x8;
typedef __attribute__((ext_vector_type(4))) float f32x4;

__device__ __forceinline__ float gelu_exact(float x) {
    return 0.5f * x * (1.0f + erff(x * 0.70710678118654752f));
}

// pack two f32 -> (lo,hi) bf16 pair in one u32 (RNE)
__device__ __forceinline__ unsigned cvtpk_bf16(float lo, float hi) {
    unsigned r;
    asm("v_cvt_pk_bf16_f32 %0, %1, %2" : "=v"(r) : "v"(lo), "v"(hi));
    return r;
}

// Pass 1 (FUSED scan+msg+wmzero): one 256-edge chunk per block (1024 blocks).
//  - gaussian gate; copy dist/edges to out
//  - LDS ballot-compaction of actives (no global counter -> no zero dep)
//  - wm-zero of this chunk's inactive rows (reuses gate flags; 100 MB total
//    drains under the matvec compute of a 1024-block BW-saturating kernel)
//  - per-wave QUAD matvec (Poisson(3.2)/block -> ~1 quad/wave, no tail):
//    224x96 @ 4 edges, GELU+LayerNorm+weight -> wm rows + agg atomics.
__global__ __launch_bounds__(256) void scanmsg_kernel(
        const float* __restrict__ dist, const int* __restrict__ edges,
        const float* __restrict__ sigma, const float* __restrict__ beta,
        const float* __restrict__ nodes, const float* __restrict__ ef,
        const float* __restrict__ Wm, const float* __restrict__ bm,
        const float* __restrict__ g1, const float* __restrict__ b1,
        float* __restrict__ out_dist, float* __restrict__ out_edges,
        float* __restrict__ out_wm, float* __restrict__ agg) {
    __shared__ int   s_ge[256];
    __shared__ float s_w[256];
    __shared__ int   s_act[256];
    __shared__ int   wcnt[4], wbase[4];
    __shared__ float sin_s[4][4][232];     // [wave][edge-in-quad][224+pad]
    int tid = threadIdx.x;
    int blk = blockIdx.x;                  // 0 .. 1023
    int ge = blk * 256 + tid;

    // ---- gate + output copies ----
    float d = dist[ge];
    out_dist[ge] = d;
    int e0s = edges[2 * ge], e1s = edges[2 * ge + 1];
    *(float2*)&out_edges[2 * ge] = make_float2((float)e0s, (float)e1s);
    float sg = sigma[0], bt = beta[0];
    float t  = d * d / (2.0f * sg * sg);
    float tp = powf(t, bt);
    bool active = (tp < 90.0f);            // else w underflows f32 (ref < 1e-39)
    float w = active ? expf(-tp) : 0.0f;
    s_act[tid] = active ? 1 : 0;

    // ---- LDS compaction (per-wave ballot, block-local prefix) ----
    unsigned long long mask = __ballot(active);
    int lane = tid & 63, wv = tid >> 6;
    int lp = __popcll(mask & ((1ull << lane) - 1ull));
    if (lane == 0) wcnt[wv] = __popcll(mask);
    __syncthreads();
    if (tid == 0) {
        int a = 0;
        #pragma unroll
        for (int i = 0; i < 4; ++i) { wbase[i] = a; a += wcnt[i]; }
    }
    __syncthreads();
    if (active) {
        int pos = wbase[wv] + lp;
        s_ge[pos] = ge;
        s_w[pos]  = w;
    }
    __syncthreads();
    int count = wbase[3] + wcnt[3];

    // ---- wm-zero of inactive rows (fire-and-forget; drains under matvec) ----
    {
        const float4 z = make_float4(0.f, 0.f, 0.f, 0.f);
        float4* wm4 = (float4*)out_wm + (size_t)blk * 6144;   // 256 rows * 24 f4
        for (int p = tid; p < 6144; p += 256) {
            if (!s_act[p / 24]) wm4[p] = z;
        }
    }

    // ---- quad matvec: wave wv handles actives [qb, qb+4) ----
    int c2 = 64 + (lane & 31);             // upper lanes duplicate lanes 0..31
    for (int qb = wv * 4; qb < count; qb += 16) {
        int   gei[4];
        float wgt[4];
        bool  val[4];
        #pragma unroll
        for (int e = 0; e < 4; ++e) {
            int ai = qb + e;
            val[e] = (ai < count);
            gei[e] = s_ge[val[e] ? ai : qb];   // clamp; padded lanes weight 0
            wgt[e] = val[e] ? s_w[ai] : 0.0f;
        }
        #pragma unroll
        for (int e = 0; e < 4; ++e) {
            int g = gei[e];
            int b = g >> 16;
            int e0 = edges[2 * g], e1 = edges[2 * g + 1];
            const float* n0 = nodes + ((size_t)b * Nn + e0) * 96;
            const float* n1 = nodes + ((size_t)b * Nn + e1) * 96;
            const float* ep = ef + (size_t)g * 32;
            #pragma unroll
            for (int ii = 0; ii < 4; ++ii) {
                int i = ii * 64 + lane;
                if (i < 224) {
                    float v = (i < 96) ? n0[i] : (i < 192) ? n1[i - 96] : ep[i - 192];
                    sin_s[wv][e][i] = v;
                }
            }
        }
        float acc[4][2];
        #pragma unroll
        for (int e = 0; e < 4; ++e) { acc[e][0] = bm[lane]; acc[e][1] = bm[c2]; }
        #pragma unroll 8
        for (int i = 0; i < 224; ++i) {
            float w1 = Wm[i * 96 + lane];
            float w2 = Wm[i * 96 + c2];
            #pragma unroll
            for (int e = 0; e < 4; ++e) {
                float a = sin_s[wv][e][i];             // LDS broadcast
                acc[e][0] = fmaf(a, w1, acc[e][0]);
                acc[e][1] = fmaf(a, w2, acc[e][1]);
            }
        }
        #pragma unroll
        for (int e = 0; e < 4; ++e) {
            if (!val[e]) continue;
            float y1 = gelu_exact(acc[e][0]);
            float y2 = gelu_exact(acc[e][1]);
            float c2v = (lane < 32) ? y2 : 0.0f;
            float sum  = y1 + c2v;
            float sum2 = y1 * y1 + c2v * c2v;
            #pragma unroll
            for (int off = 1; off < 64; off <<= 1) {
                sum  += __shfl_xor(sum, off);
                sum2 += __shfl_xor(sum2, off);
            }
            float mean = sum * (1.0f / 96.0f);
            float var  = sum2 * (1.0f / 96.0f) - mean * mean;
            float rs   = rsqrtf(var + 1e-3f);
            int g = gei[e];
            int b = g >> 16;
            int e1 = edges[2 * g + 1];
            float* aggp = agg + ((size_t)b * Nn + e1) * 96;
            float* wmp  = out_wm + (size_t)g * 96;
            float o1 = ((y1 - mean) * rs * g1[lane] + b1[lane]) * wgt[e];
            wmp[lane] = o1;
            atomicAdd(&aggp[lane], o1);
            if (lane < 32) {
                float o2 = ((y2 - mean) * rs * g1[c2] + b1[c2]) * wgt[e];
                wmp[c2] = o2;
                atomicAdd(&aggp[c2], o2);
            }
        }
    }
}

// Pass 2 (proj): W staged in LDS, read at wave-uniform addresses (hardware
// broadcast); X transposed xs[k][row] (stride 64, conflict-free). Wave w
// handles cols w*24..+23 for 64 rows (row = lane). 1 block/CU (120 KB LDS).
__global__ __launch_bounds__(256, 1) void proj_kernel(
        const float* __restrict__ nodes, const float* __restrict__ agg,
        const float* __restrict__ Wq, const float* __restrict__ bq,
        const float* __restrict__ Wk, const float* __restrict__ bk,
        const float* __restrict__ Wv, const float* __restrict__ bv,
        const float* __restrict__ Wg, const float* __restrict__ bg,
        float* __restrict__ qo, float* __restrict__ ko,
        float* __restrict__ vo, float* __restrict__ go) {
    __shared__ float xs[192][64];   // transposed X tile, 49152 B
    __shared__ float Ws[192 * 96];  // 73728 B
    int tid = threadIdx.x;
    int m = blockIdx.y;
    const float* W    = (m == 0) ? Wq : (m == 1) ? Wk : (m == 2) ? Wv : Wg;
    const float* bias = (m == 0) ? bq : (m == 1) ? bk : (m == 2) ? bv : bg;
    float* outp       = (m == 0) ? qo : (m == 1) ? ko : (m == 2) ? vo : go;
    int row0 = blockIdx.x * 64;
    int b = row0 >> 10, n0 = row0 & 1023;

    {
        float4* Ws4 = (float4*)Ws;
        const float4* Wg4 = (const float4*)W;
        for (int i = tid; i < 4608; i += 256) Ws4[i] = Wg4[i];
    }
    for (int i = tid; i < 3072; i += 256) {
        int r = i & 63, k4 = i >> 6;
        size_t row = (size_t)row0 + r;
        float4 v = (k4 < 24) ? *(const float4*)&nodes[row * 96 + k4 * 4]
                             : *(const float4*)&agg[row * 96 + (k4 - 24) * 4];
        int k = k4 * 4;
        xs[k][r] = v.x; xs[k + 1][r] = v.y; xs[k + 2][r] = v.z; xs[k + 3][r] = v.w;
    }
    __syncthreads();

    int lane = tid & 63;
    int wcol = __builtin_amdgcn_readfirstlane((tid >> 6) * 24);
    float acc[24];
    #pragma unroll
    for (int c = 0; c < 24; ++c) acc[c] = bias[wcol + c];
    for (int k = 0; k < 192; ++k) {
        float a = xs[k][lane];                 // conflict-free
        const float* wr = &Ws[k * 96 + wcol];  // wave-uniform -> LDS broadcast
        #pragma unroll
        for (int c = 0; c < 24; ++c)
            acc[c] = fmaf(a, wr[c], acc[c]);
    }
    if (m == 3) {
        #pragma unroll
        for (int c = 0; c < 24; ++c) acc[c] = 1.0f / (1.0f + expf(-acc[c]));
    }
    float4* out4 = (float4*)outp;
    int h0 = wcol >> 3;               // 24 cols = 3 heads
    #pragma unroll
    for (int hh = 0; hh < 3; ++hh) {
        size_t base = (((size_t)b * Hn + (h0 + hh)) * Nn + (n0 + lane)) * 2;
        out4[base]     = make_float4(acc[hh*8+0], acc[hh*8+1], acc[hh*8+2], acc[hh*8+3]);
        out4[base + 1] = make_float4(acc[hh*8+4], acc[hh*8+5], acc[hh*8+6], acc[hh*8+7]);
    }
}

// Pass 3: MFMA bf16 attention (pure compute now; wm-zero moved to scanmsg).
// K staged bf16 [1024][8]; V staged transposed [9][1032] with ones-row 8 so
// the PV MFMA accumulates the softmax denominator L into O col 8 for free.
// No-max softmax (scores |s|<~20 << 88 f32 exp overflow).
__global__ __launch_bounds__(256, 4) void attn_kernel(
        const float* __restrict__ qp, const float* __restrict__ kp,
        const float* __restrict__ vp, const float* __restrict__ gp,
        float* __restrict__ ao) {
    __shared__ __align__(16) unsigned short K_s[1024][8];     // 16 KB
    __shared__ __align__(16) unsigned short Vt_s[9][1032];    // 18.1 KB
    __shared__ __align__(16) unsigned short P_s[4][16][32];   // 4 KB
    int tid = threadIdx.x;
    int bh = blockIdx.y;                    // b*H + h
    int lane = tid & 63, wv = tid >> 6;
    size_t hb = (size_t)bh * (Nn * 8);
    const float* kc = kp + hb;
    const float* vc = vp + hb;

    // ---- stage K as bf16 [k][d] ----
    {
        const float2* k2 = (const float2*)kc;
        unsigned* kw = (unsigned*)&K_s[0][0];
        for (int i = tid; i < 4096; i += 256) {
            float2 v = k2[i];
            kw[i] = cvtpk_bf16(v.x, v.y);
        }
    }
    // ---- stage V transposed via k-pairs ----
    {
        const float4* v4 = (const float4*)vc;
        for (int i = tid; i < 1024; i += 256) {
            int kp2 = i >> 1, dq = i & 1;
            float4 a = v4[kp2 * 4 + dq];       // V[2kp][dq*4..+3]
            float4 b = v4[kp2 * 4 + 2 + dq];   // V[2kp+1][dq*4..+3]
            int d0 = dq * 4;
            ((unsigned*)&Vt_s[d0 + 0][0])[kp2] = cvtpk_bf16(a.x, b.x);
            ((unsigned*)&Vt_s[d0 + 1][0])[kp2] = cvtpk_bf16(a.y, b.y);
            ((unsigned*)&Vt_s[d0 + 2][0])[kp2] = cvtpk_bf16(a.z, b.z);
            ((unsigned*)&Vt_s[d0 + 3][0])[kp2] = cvtpk_bf16(a.w, b.w);
        }
        unsigned* ow = (unsigned*)&Vt_s[8][0];
        for (int i = tid; i < 516; i += 256) ow[i] = 0x3F803F80u;  // bf16(1.0) x2
    }
    const float scale = 0.35355339059327376f;
    int qbase = blockIdx.x * 64 + wv * 16;
    bf16x8 aq = {0, 0, 0, 0, 0, 0, 0, 0};
    if (lane < 16) {
        const float* qr = qp + hb + (size_t)(qbase + lane) * 8;
        float4 qa = *(const float4*)qr;
        float4 qb2 = *(const float4*)(qr + 4);
        union { unsigned u[4]; bf16x8 v; } U;
        U.u[0] = cvtpk_bf16(qa.x * scale, qa.y * scale);
        U.u[1] = cvtpk_bf16(qa.z * scale, qa.w * scale);
        U.u[2] = cvtpk_bf16(qb2.x * scale, qb2.y * scale);
        U.u[3] = cvtpk_bf16(qb2.z * scale, qb2.w * scale);
        aq = U.v;
    }
    __syncthreads();

    const bf16x8 zero8 = {0, 0, 0, 0, 0, 0, 0, 0};
    const f32x4 zero4 = {0.f, 0.f, 0.f, 0.f};
    f32x4 o = zero4;
    int n16 = lane & 15, grp = lane >> 4;
    for (int c = 0; c < 32; ++c) {
        bf16x8 bk0 = zero8, bk1 = zero8;
        if (lane < 16) {
            bk0 = *(const bf16x8*)&K_s[c * 32 + lane][0];
            bk1 = *(const bf16x8*)&K_s[c * 32 + 16 + lane][0];
        }
        f32x4 s0 = __builtin_amdgcn_mfma_f32_16x16x32_bf16(aq, bk0, zero4, 0, 0, 0);
        f32x4 s1 = __builtin_amdgcn_mfma_f32_16x16x32_bf16(aq, bk1, zero4, 0, 0, 0);
        #pragma unroll
        for (int r = 0; r < 4; ++r) {
            unsigned pk = cvtpk_bf16(__expf(s0[r]), __expf(s1[r]));
            int row = grp * 4 + r;
            P_s[wv][row][n16]      = (unsigned short)pk;
            P_s[wv][row][16 + n16] = (unsigned short)(pk >> 16);
        }
        bf16x8 pa = *(const bf16x8*)&P_s[wv][n16][grp * 8];
        bf16x8 bv = zero8;
        if (n16 <= 8) bv = *(const bf16x8*)&Vt_s[n16][c * 32 + grp * 8];
        o = __builtin_amdgcn_mfma_f32_16x16x32_bf16(pa, bv, o, 0, 0, 0);
    }

    #pragma unroll
    for (int r = 0; r < 4; ++r) {
        float L = __shfl(o[r], (lane & 48) | 8);
        if (n16 < 8) {
            int q = qbase + grp * 4 + r;
            size_t off = hb + (size_t)q * 8 + n16;
            ao[off] = o[r] / L * gp[off];
        }
    }
}

// Pass 4 (out): broadcast-W structure. Wave w = cols w*24..+23, row = lane
// (64 rows/block); as_[k][row] conflict-free; Wo in LDS; cross-wave LN reduce.
__global__ __launch_bounds__(256) void out_kernel(
        const float* __restrict__ ao, const float* __restrict__ Wo,
        const float* __restrict__ bo, const float* __restrict__ g2,
        const float* __restrict__ b2, float* __restrict__ out0) {
    __shared__ float as_[96][64];      // 24576 B
    __shared__ float Ws[96 * 96];      // 36864 B
    __shared__ float2 red_s[4][64];    // 2048 B
    int tid = threadIdx.x;
    int row0 = blockIdx.x * 64;
    int b = row0 >> 10, n0 = row0 & 1023;
    {
        float4* W4 = (float4*)Ws;
        const float4* Wg4 = (const float4*)Wo;
        for (int i = tid; i < 2304; i += 256) W4[i] = Wg4[i];
    }
    const float2* ao2 = (const float2*)ao;
    for (int i = tid; i < 3072; i += 256) {       // 64 n * 48 (h, dpair)
        int n = i & 63, hd = i >> 6;              // hd = h*4 + dpair
        int h = hd >> 2, dp = hd & 3;
        float2 v = ao2[(((size_t)b * Hn + h) * Nn + (n0 + n)) * 4 + dp];
        as_[h * 8 + dp * 2][n]     = v.x;
        as_[h * 8 + dp * 2 + 1][n] = v.y;
    }
    __syncthreads();
    int lane = tid & 63, w = tid >> 6;
    int wcol = __builtin_amdgcn_readfirstlane(w * 24);
    float acc[24];
    #pragma unroll
    for (int c = 0; c < 24; ++c) acc[c] = bo[wcol + c];
    for (int k = 0; k < 96; ++k) {
        float a = as_[k][lane];                // conflict-free
        const float* wr = &Ws[k * 96 + wcol];  // wave-uniform -> broadcast
        #pragma unroll
        for (int c = 0; c < 24; ++c)
            acc[c] = fmaf(a, wr[c], acc[c]);
    }
    float y[24];
    float sum = 0.0f, sum2 = 0.0f;
    #pragma unroll
    for (int c = 0; c < 24; ++c) {
        float g = gelu_exact(acc[c]);
        y[c] = g; sum += g; sum2 += g * g;
    }
    red_s[w][lane] = make_float2(sum, sum2);
    __syncthreads();
    float S = 0.0f, S2 = 0.0f;
    #pragma unroll
    for (int i = 0; i < 4; ++i) { float2 p = red_s[i][lane]; S += p.x; S2 += p.y; }
    float mean = S * (1.0f / 96.0f);
    float var  = S2 * (1.0f / 96.0f) - mean * mean;
    float rs   = rsqrtf(var + 1e-3f);
    size_t row = (size_t)row0 + lane;
    #pragma unroll
    for (int c = 0; c < 24; ++c)
        y[c] = (y[c] - mean) * rs * g2[wcol + c] + b2[wcol + c];
    float4* o4 = (float4*)&out0[row * 96 + wcol];
    #pragma unroll
    for (int q = 0; q < 6; ++q)
        o4[q] = make_float4(y[q*4], y[q*4+1], y[q*4+2], y[q*4+3]);
}

extern "C" void kernel_launch(void* const* d_in, const int* in_sizes, int n_in,
                              void* d_out, int out_size, void* d_ws, size_t ws_size,
                              hipStream_t stream) {
    const float* nodes = (const float*)d_in[0];
    const float* ef    = (const float*)d_in[1];
    const float* dist  = (const float*)d_in[2];
    const int*   edges = (const int*)d_in[3];
    const float* Wm = (const float*)d_in[4];
    const float* bm = (const float*)d_in[5];
    const float* g1 = (const float*)d_in[6];
    const float* b1 = (const float*)d_in[7];
    const float* Wq = (const float*)d_in[8];
    const float* bq = (const float*)d_in[9];
    const float* Wk = (const float*)d_in[10];
    const float* bk = (const float*)d_in[11];
    const float* Wv = (const float*)d_in[12];
    const float* bv = (const float*)d_in[13];
    const float* Wg = (const float*)d_in[14];
    const float* bg = (const float*)d_in[15];
    const float* Wo = (const float*)d_in[16];
    const float* bo = (const float*)d_in[17];
    const float* g2 = (const float*)d_in[18];
    const float* b2 = (const float*)d_in[19];
    const float* sigma = (const float*)d_in[20];
    const float* beta  = (const float*)d_in[21];

    float* out = (float*)d_out;
    float* ws  = (float*)d_ws;

    float* agg  = ws + WS_AGG;
    float* qb   = ws + WS_Q;
    float* kb   = ws + WS_K;
    float* vb   = ws + WS_V;
    float* gwb  = ws + WS_G;
    float* aob  = ws + WS_AO;

    hipMemsetAsync(agg, 0, (size_t)Bn * Nn * Fn * sizeof(float), stream);

    scanmsg_kernel<<<Bn * En / 256, 256, 0, stream>>>(
        dist, edges, sigma, beta, nodes, ef, Wm, bm, g1, b1,
        out + OUT_DIST, out + OUT_EDGE, out + OUT_WM, agg);

    dim3 gp_(64, 4);
    proj_kernel<<<gp_, 256, 0, stream>>>(
        nodes, agg, Wq, bq, Wk, bk, Wv, bv, Wg, bg, qb, kb, vb, gwb);

    dim3 ga(16, Bn * Hn);
    attn_kernel<<<ga, 256, 0, stream>>>(qb, kb, vb, gwb, aob);

    out_kernel<<<Bn * Nn / 64, 256, 0, stream>>>(aob, Wo, bo, g2, b2, out + OUT_UPD);
}